// Round 5
// baseline (201.312 us; speedup 1.0000x reference)
//
#include <hip/hip_runtime.h>

#define BATCH 16
#define SEQ   4096
#define DIM   64
#define WIN   512

constexpr int BM = 128;       // q rows per block
constexpr int BN = 64;        // keys per tile
constexpr int NTHREADS = 256; // 4 waves; each wave owns 32 q rows (2 groups of 16)
constexpr int KS = DIM + 8;   // Ksh row stride (f16 elems)
constexpr int VS = BN + 4;    // Vsh row stride (f16 elems)
constexpr int OS = DIM + 4;   // Osh row stride (f32 elems)
// fold softmax scale and log2(e) into Q so p = exp2(s - m)
constexpr float QSCALE  = 0.125f * 1.44269504088896340736f;
constexpr float MASKVAL = -3.0e38f;   // << m_run init (-1e30) so masked lanes give p=0

typedef _Float16 f16x2 __attribute__((ext_vector_type(2)));
typedef _Float16 f16x4 __attribute__((ext_vector_type(4)));
typedef _Float16 f16x8 __attribute__((ext_vector_type(8)));
typedef float    f32x4 __attribute__((ext_vector_type(4)));

__device__ __forceinline__ f16x2 pk2(float a, float b) {
    return __builtin_bit_cast(f16x2, __builtin_amdgcn_cvt_pkrtz(a, b));
}

__device__ __forceinline__ void stage_kv(_Float16* __restrict__ Ksh, _Float16* __restrict__ Vsh,
                                         const float4& kv, const float4& vv,
                                         int row, int c4) {
    union { f16x4 v; f16x2 h[2]; } uk;
    uk.h[0] = pk2(kv.x, kv.y);
    uk.h[1] = pk2(kv.z, kv.w);
    *(f16x4*)&Ksh[row * KS + c4] = uk.v;
    Vsh[(c4 + 0) * VS + row] = (_Float16)vv.x;
    Vsh[(c4 + 1) * VS + row] = (_Float16)vv.y;
    Vsh[(c4 + 2) * VS + row] = (_Float16)vv.z;
    Vsh[(c4 + 3) * VS + row] = (_Float16)vv.w;
}

// load one group's Q B-frags (16x16x32: lane holds Q[q][chunk*32 + quad*8 + j])
__device__ __forceinline__ void load_qfrag(const float* __restrict__ qb, int q, int quad,
                                           f16x8& qf0, f16x8& qf1) {
    const float* qp = qb + (size_t)q * DIM + quad * 8;
    const float4 a0 = *(const float4*)(qp + 0);
    const float4 a1 = *(const float4*)(qp + 4);
    const float4 a2 = *(const float4*)(qp + 32);
    const float4 a3 = *(const float4*)(qp + 36);
    union { f16x8 v; f16x2 h[4]; } u0, u1;
    u0.h[0] = pk2(a0.x * QSCALE, a0.y * QSCALE);
    u0.h[1] = pk2(a0.z * QSCALE, a0.w * QSCALE);
    u0.h[2] = pk2(a1.x * QSCALE, a1.y * QSCALE);
    u0.h[3] = pk2(a1.z * QSCALE, a1.w * QSCALE);
    u1.h[0] = pk2(a2.x * QSCALE, a2.y * QSCALE);
    u1.h[1] = pk2(a2.z * QSCALE, a2.w * QSCALE);
    u1.h[2] = pk2(a3.x * QSCALE, a3.y * QSCALE);
    u1.h[3] = pk2(a3.z * QSCALE, a3.w * QSCALE);
    qf0 = u0.v; qf1 = u1.v;
}

// online-softmax update for one 16-q group over one 64-key tile
__device__ __forceinline__ void softmax_update(f32x4 (&sc)[4], float& m_run, float& l_run,
                                               f16x4 (&pb)[4], f32x4 (&o)[4],
                                               int kbase, int g16, int q, int quad) {
    const bool edge = (kbase < g16 + 15 - (WIN - 1)) || (kbase + BN - 1 > g16);
    if (edge) {
        #pragma unroll
        for (int mt = 0; mt < 4; ++mt) {
            #pragma unroll
            for (int r = 0; r < 4; ++r) {
                const int key = kbase + mt * 16 + quad * 4 + r;
                sc[mt][r] = ((unsigned)(q - key) < (unsigned)WIN) ? sc[mt][r] : MASKVAL;
            }
        }
    }
    float mt_ = MASKVAL;
    #pragma unroll
    for (int mtile = 0; mtile < 4; ++mtile)
        #pragma unroll
        for (int r = 0; r < 4; ++r) mt_ = fmaxf(mt_, sc[mtile][r]);
    mt_ = fmaxf(mt_, __shfl_xor(mt_, 16));
    mt_ = fmaxf(mt_, __shfl_xor(mt_, 32));
    const float mn    = fmaxf(m_run, mt_);
    const float alpha = exp2f(m_run - mn);
    m_run = mn;

    float ls = 0.f;
    #pragma unroll
    for (int nt = 0; nt < 4; ++nt) {
        const float p0 = exp2f(sc[nt][0] - mn);
        const float p1 = exp2f(sc[nt][1] - mn);
        const float p2 = exp2f(sc[nt][2] - mn);
        const float p3 = exp2f(sc[nt][3] - mn);
        ls += (p0 + p1) + (p2 + p3);
        union { f16x4 v; f16x2 h[2]; } up;
        up.h[0] = pk2(p0, p1);
        up.h[1] = pk2(p2, p3);
        pb[nt] = up.v;
    }
    l_run = l_run * alpha + ls;
    #pragma unroll
    for (int mi = 0; mi < 4; ++mi) o[mi] = o[mi] * alpha;
}

__global__ __launch_bounds__(NTHREADS, 2)
void swa_kernel(const float* __restrict__ qg, const float* __restrict__ kg,
                const float* __restrict__ vg, float* __restrict__ outg) {
    // staging: Ksh [BN][KS] f16 (9216 B) | Vsh [DIM][VS] f16 (8704 B) = 17920 B
    // epilogue: Osh f32 [BM][OS] = 34816 B (overlays staging)
    __shared__ __align__(16) char smem[BM * OS * 4];
    _Float16* Ksh = (_Float16*)smem;
    _Float16* Vsh = (_Float16*)(smem + BN * KS * 2);
    float*    Osh = (float*)smem;

    const int tid  = threadIdx.x;
    const int lane = tid & 63;
    const int wave = tid >> 6;     // 0..3
    const int lr   = lane & 15;
    const int quad = lane >> 4;

    const int b     = blockIdx.y;
    const int qblk  = blockIdx.x;
    const int qrow0 = qblk * BM;
    const int wr0   = qrow0 + wave * 32;  // wave's first q row (owns 32)
    const int g16_0 = wr0;                // group 0 base
    const int g16_1 = wr0 + 16;           // group 1 base
    const int q0    = g16_0 + lr;
    const int q1    = g16_1 + lr;

    const float* qb = qg + (size_t)b * SEQ * DIM;
    const float* kb = kg + (size_t)b * SEQ * DIM;
    const float* vb = vg + (size_t)b * SEQ * DIM;
    float*       ob = outg + (size_t)b * SEQ * DIM;

    // staging thread->slot map (four 16-row quarters per tile)
    const int row0 = tid >> 4;            // 0..15
    const int c4   = (tid & 15) * 4;      // 0..60

    f16x8 qf0a, qf1a, qf0b, qf1b;
    load_qfrag(qb, q0, quad, qf0a, qf1a);
    load_qfrag(qb, q1, quad, qf0b, qf1b);

    f32x4 o0[4], o1[4];
    #pragma unroll
    for (int mi = 0; mi < 4; ++mi) {
        o0[mi] = (f32x4){0.f, 0.f, 0.f, 0.f};
        o1[mi] = (f32x4){0.f, 0.f, 0.f, 0.f};
    }
    float m0 = -1e30f, l0 = 0.f;
    float m1 = -1e30f, l1 = 0.f;

    const int t0 = (qrow0 > (WIN - 1)) ? (qrow0 - (WIN - 1)) >> 6 : 0;
    const int t1 = (qrow0 + BM - 1) >> 6;

    // ---- prologue: stage tile t0 directly ----
    #pragma unroll
    for (int i = 0; i < 4; ++i) {
        const int row = row0 + 16 * i;
        const size_t g = (size_t)(t0 * BN + row) * DIM + c4;
        stage_kv(Ksh, Vsh, *(const float4*)&kb[g], *(const float4*)&vb[g], row, c4);
    }
    __syncthreads();

    for (int t = t0; t <= t1; ++t) {
        const bool have_next = (t < t1);
        float4 kpre[4], vpre[4];
        if (have_next) {
            // issue next tile's global loads NOW; consumed after the raw barrier,
            // so they stay in flight across compute (no vmcnt(0) drain)
            #pragma unroll
            for (int i = 0; i < 4; ++i) {
                const size_t g = (size_t)((t + 1) * BN + row0 + 16 * i) * DIM + c4;
                kpre[i] = *(const float4*)&kb[g];
                vpre[i] = *(const float4*)&vb[g];
            }
        }

        const int kbase = t * BN;
        // per-group activity (wave-uniform)
        const bool act0 = (kbase <= g16_0 + 15) && (kbase + BN - 1 >= g16_0 - (WIN - 1));
        const bool act1 = (kbase <= g16_1 + 15) && (kbase + BN - 1 >= g16_1 - (WIN - 1));

        if (act0 || act1) {
            // ---- S^T = K * Q^T : shared K-frags feed both q-groups ----
            f32x4 s0[4], s1[4];
            #pragma unroll
            for (int mt = 0; mt < 4; ++mt) {
                const f16x8 kf0 = *(const f16x8*)&Ksh[(mt * 16 + lr) * KS + quad * 8];
                const f16x8 kf1 = *(const f16x8*)&Ksh[(mt * 16 + lr) * KS + 32 + quad * 8];
                if (act0) {
                    f32x4 s = (f32x4){0.f, 0.f, 0.f, 0.f};
                    s = __builtin_amdgcn_mfma_f32_16x16x32_f16(kf0, qf0a, s, 0, 0, 0);
                    s = __builtin_amdgcn_mfma_f32_16x16x32_f16(kf1, qf1a, s, 0, 0, 0);
                    s0[mt] = s;
                }
                if (act1) {
                    f32x4 s = (f32x4){0.f, 0.f, 0.f, 0.f};
                    s = __builtin_amdgcn_mfma_f32_16x16x32_f16(kf0, qf0b, s, 0, 0, 0);
                    s = __builtin_amdgcn_mfma_f32_16x16x32_f16(kf1, qf1b, s, 0, 0, 0);
                    s1[mt] = s;
                }
            }

            f16x4 pb0[4], pb1[4];
            if (act0) softmax_update(s0, m0, l0, pb0, o0, kbase, g16_0, q0, quad);
            if (act1) softmax_update(s1, m1, l1, pb1, o1, kbase, g16_1, q1, quad);

            // ---- O^T += V^T * P^T : shared V-frags feed both q-groups ----
            #pragma unroll
            for (int nt = 0; nt < 4; ++nt) {
                #pragma unroll
                for (int mi = 0; mi < 4; ++mi) {
                    const f16x4 vf = *(const f16x4*)&Vsh[(mi * 16 + lr) * VS + nt * 16 + quad * 4];
                    if (act0) o0[mi] = __builtin_amdgcn_mfma_f32_16x16x16f16(vf, pb0[nt], o0[mi], 0, 0, 0);
                    if (act1) o1[mi] = __builtin_amdgcn_mfma_f32_16x16x16f16(vf, pb1[nt], o1[mi], 0, 0, 0);
                }
            }
        }

        // raw barrier: LDS read results already consumed (lgkmcnt waits precede MFMA
        // use); prefetch global loads must NOT be drained here -> no __syncthreads
        __builtin_amdgcn_s_barrier();
        if (have_next) {
            #pragma unroll
            for (int i = 0; i < 4; ++i)
                stage_kv(Ksh, Vsh, kpre[i], vpre[i], row0 + 16 * i, c4);
        }
        __syncthreads();   // ds_writes visible; prefetch already consumed, no extra drain
    }

    // ---- epilogue: l reduce across quads, normalize, transpose via LDS, store ----
    l0 += __shfl_xor(l0, 16); l0 += __shfl_xor(l0, 32);
    l1 += __shfl_xor(l1, 16); l1 += __shfl_xor(l1, 32);
    const float inv0 = 1.0f / l0;
    const float inv1 = 1.0f / l1;

    float* Ow = Osh + wave * 32 * OS;   // per-wave private 32 x OS region
    #pragma unroll
    for (int mi = 0; mi < 4; ++mi) {
        float4 st0, st1;
        st0.x = o0[mi][0] * inv0; st0.y = o0[mi][1] * inv0;
        st0.z = o0[mi][2] * inv0; st0.w = o0[mi][3] * inv0;
        *(float4*)&Ow[lr * OS + mi * 16 + quad * 4] = st0;
        st1.x = o1[mi][0] * inv1; st1.y = o1[mi][1] * inv1;
        st1.z = o1[mi][2] * inv1; st1.w = o1[mi][3] * inv1;
        *(float4*)&Ow[(16 + lr) * OS + mi * 16 + quad * 4] = st1;
    }
    #pragma unroll
    for (int j = 0; j < 8; ++j) {
        const int qq = quad + 4 * j;        // 0..31
        const int d4 = lr * 4;
        const float4 vst = *(const float4*)&Ow[qq * OS + d4];
        *(float4*)&ob[(size_t)(wr0 + qq) * DIM + d4] = vst;
    }
}

extern "C" void kernel_launch(void* const* d_in, const int* in_sizes, int n_in,
                              void* d_out, int out_size, void* d_ws, size_t ws_size,
                              hipStream_t stream) {
    (void)in_sizes; (void)n_in; (void)out_size; (void)d_ws; (void)ws_size;
    const float* q = (const float*)d_in[0];
    const float* k = (const float*)d_in[1];
    const float* v = (const float*)d_in[2];
    float* out = (float*)d_out;
    dim3 grid(SEQ / BM, BATCH);
    swa_kernel<<<grid, dim3(NTHREADS), 0, stream>>>(q, k, v, out);
}

// Round 6
// 189.809 us; speedup vs baseline: 1.0606x; 1.0606x over previous
//
#include <hip/hip_runtime.h>

#define BATCH 16
#define SEQ   4096
#define DIM   64
#define WIN   512

constexpr int BM = 128;       // q rows per block
constexpr int BN = 64;        // keys per tile
constexpr int NTHREADS = 256; // 4 waves; each wave owns 32 q rows (2 groups of 16)
constexpr int KS = DIM + 8;   // Ksh row stride (f16 elems)
constexpr int VS = BN + 4;    // Vsh row stride (f16 elems)
constexpr int OS = DIM + 4;   // Osh row stride (f32 elems)
// fold softmax scale and log2(e) into Q so p = exp2(s - m)
constexpr float QSCALE  = 0.125f * 1.44269504088896340736f;
constexpr float MASKVAL = -3.0e38f;   // << m_run init (-1e30) so masked lanes give p=0

typedef _Float16 f16x2 __attribute__((ext_vector_type(2)));
typedef _Float16 f16x4 __attribute__((ext_vector_type(4)));
typedef _Float16 f16x8 __attribute__((ext_vector_type(8)));
typedef float    f32x4 __attribute__((ext_vector_type(4)));

__device__ __forceinline__ f16x2 pk2(float a, float b) {
    return __builtin_bit_cast(f16x2, __builtin_amdgcn_cvt_pkrtz(a, b));
}

__device__ __forceinline__ void stage_kv(_Float16* __restrict__ Ksh, _Float16* __restrict__ Vsh,
                                         const float4& kv, const float4& vv,
                                         int row, int c4) {
    union { f16x4 v; f16x2 h[2]; } uk;
    uk.h[0] = pk2(kv.x, kv.y);
    uk.h[1] = pk2(kv.z, kv.w);
    *(f16x4*)&Ksh[row * KS + c4] = uk.v;
    Vsh[(c4 + 0) * VS + row] = (_Float16)vv.x;
    Vsh[(c4 + 1) * VS + row] = (_Float16)vv.y;
    Vsh[(c4 + 2) * VS + row] = (_Float16)vv.z;
    Vsh[(c4 + 3) * VS + row] = (_Float16)vv.w;
}

// load one group's Q B-frags (16x16x32: lane holds Q[q][chunk*32 + quad*8 + j])
__device__ __forceinline__ void load_qfrag(const float* __restrict__ qb, int q, int quad,
                                           f16x8& qf0, f16x8& qf1) {
    const float* qp = qb + (size_t)q * DIM + quad * 8;
    const float4 a0 = *(const float4*)(qp + 0);
    const float4 a1 = *(const float4*)(qp + 4);
    const float4 a2 = *(const float4*)(qp + 32);
    const float4 a3 = *(const float4*)(qp + 36);
    union { f16x8 v; f16x2 h[4]; } u0, u1;
    u0.h[0] = pk2(a0.x * QSCALE, a0.y * QSCALE);
    u0.h[1] = pk2(a0.z * QSCALE, a0.w * QSCALE);
    u0.h[2] = pk2(a1.x * QSCALE, a1.y * QSCALE);
    u0.h[3] = pk2(a1.z * QSCALE, a1.w * QSCALE);
    u1.h[0] = pk2(a2.x * QSCALE, a2.y * QSCALE);
    u1.h[1] = pk2(a2.z * QSCALE, a2.w * QSCALE);
    u1.h[2] = pk2(a3.x * QSCALE, a3.y * QSCALE);
    u1.h[3] = pk2(a3.z * QSCALE, a3.w * QSCALE);
    qf0 = u0.v; qf1 = u1.v;
}

// online-softmax update for one 16-q group over one 64-key tile
__device__ __forceinline__ void softmax_update(f32x4 (&sc)[4], float& m_run, float& l_run,
                                               f16x4 (&pb)[4], f32x4 (&o)[4],
                                               int kbase, int g16, int q, int quad) {
    const bool edge = (kbase < g16 + 15 - (WIN - 1)) || (kbase + BN - 1 > g16);
    if (edge) {
        #pragma unroll
        for (int mt = 0; mt < 4; ++mt) {
            #pragma unroll
            for (int r = 0; r < 4; ++r) {
                const int key = kbase + mt * 16 + quad * 4 + r;
                sc[mt][r] = ((unsigned)(q - key) < (unsigned)WIN) ? sc[mt][r] : MASKVAL;
            }
        }
    }
    float mt_ = MASKVAL;
    #pragma unroll
    for (int mtile = 0; mtile < 4; ++mtile)
        #pragma unroll
        for (int r = 0; r < 4; ++r) mt_ = fmaxf(mt_, sc[mtile][r]);
    mt_ = fmaxf(mt_, __shfl_xor(mt_, 16));
    mt_ = fmaxf(mt_, __shfl_xor(mt_, 32));
    const float mn    = fmaxf(m_run, mt_);
    const float alpha = exp2f(m_run - mn);
    m_run = mn;

    float ls = 0.f;
    #pragma unroll
    for (int nt = 0; nt < 4; ++nt) {
        const float p0 = exp2f(sc[nt][0] - mn);
        const float p1 = exp2f(sc[nt][1] - mn);
        const float p2 = exp2f(sc[nt][2] - mn);
        const float p3 = exp2f(sc[nt][3] - mn);
        ls += (p0 + p1) + (p2 + p3);
        union { f16x4 v; f16x2 h[2]; } up;
        up.h[0] = pk2(p0, p1);
        up.h[1] = pk2(p2, p3);
        pb[nt] = up.v;
    }
    l_run = l_run * alpha + ls;
    #pragma unroll
    for (int mi = 0; mi < 4; ++mi) o[mi] = o[mi] * alpha;
}

// NOTE: no min-waves arg — (256,2) clamped VGPR to 128 and spilled s0/s1 every
// tile (R5: WRITE_SIZE 82 MB). Free allocation (~180 VGPR) still yields 8 waves/CU.
__global__ __launch_bounds__(NTHREADS)
void swa_kernel(const float* __restrict__ qg, const float* __restrict__ kg,
                const float* __restrict__ vg, float* __restrict__ outg) {
    // staging: Ksh [BN][KS] f16 (9216 B) | Vsh [DIM][VS] f16 (8704 B) = 17920 B
    // epilogue: Osh f32 [BM][OS] = 34816 B (overlays staging)
    __shared__ __align__(16) char smem[BM * OS * 4];
    _Float16* Ksh = (_Float16*)smem;
    _Float16* Vsh = (_Float16*)(smem + BN * KS * 2);
    float*    Osh = (float*)smem;

    const int tid  = threadIdx.x;
    const int lane = tid & 63;
    const int wave = tid >> 6;     // 0..3
    const int lr   = lane & 15;
    const int quad = lane >> 4;

    const int b     = blockIdx.y;
    const int qblk  = blockIdx.x;
    const int qrow0 = qblk * BM;
    const int wr0   = qrow0 + wave * 32;  // wave's first q row (owns 32)
    const int g16_0 = wr0;                // group 0 base
    const int g16_1 = wr0 + 16;           // group 1 base
    const int q0    = g16_0 + lr;
    const int q1    = g16_1 + lr;

    const float* qb = qg + (size_t)b * SEQ * DIM;
    const float* kb = kg + (size_t)b * SEQ * DIM;
    const float* vb = vg + (size_t)b * SEQ * DIM;
    float*       ob = outg + (size_t)b * SEQ * DIM;

    // staging thread->slot map (four 16-row quarters per tile)
    const int row0 = tid >> 4;            // 0..15
    const int c4   = (tid & 15) * 4;      // 0..60

    f16x8 qf0a, qf1a, qf0b, qf1b;
    load_qfrag(qb, q0, quad, qf0a, qf1a);
    load_qfrag(qb, q1, quad, qf0b, qf1b);

    f32x4 o0[4], o1[4];
    #pragma unroll
    for (int mi = 0; mi < 4; ++mi) {
        o0[mi] = (f32x4){0.f, 0.f, 0.f, 0.f};
        o1[mi] = (f32x4){0.f, 0.f, 0.f, 0.f};
    }
    float m0 = -1e30f, l0 = 0.f;
    float m1 = -1e30f, l1 = 0.f;

    const int t0 = (qrow0 > (WIN - 1)) ? (qrow0 - (WIN - 1)) >> 6 : 0;
    const int t1 = (qrow0 + BM - 1) >> 6;

    // ---- prologue: stage tile t0 directly ----
    #pragma unroll
    for (int i = 0; i < 4; ++i) {
        const int row = row0 + 16 * i;
        const size_t g = (size_t)(t0 * BN + row) * DIM + c4;
        stage_kv(Ksh, Vsh, *(const float4*)&kb[g], *(const float4*)&vb[g], row, c4);
    }
    __syncthreads();

    for (int t = t0; t <= t1; ++t) {
        const bool have_next = (t < t1);
        float4 kpre[4], vpre[4];
        if (have_next) {
            // issue next tile's global loads NOW; consumed after the raw barrier,
            // so they stay in flight across compute (no vmcnt(0) drain)
            #pragma unroll
            for (int i = 0; i < 4; ++i) {
                const size_t g = (size_t)((t + 1) * BN + row0 + 16 * i) * DIM + c4;
                kpre[i] = *(const float4*)&kb[g];
                vpre[i] = *(const float4*)&vb[g];
            }
        }

        const int kbase = t * BN;
        // per-group activity (wave-uniform)
        const bool act0 = (kbase <= g16_0 + 15) && (kbase + BN - 1 >= g16_0 - (WIN - 1));
        const bool act1 = (kbase <= g16_1 + 15) && (kbase + BN - 1 >= g16_1 - (WIN - 1));

        if (act0 || act1) {
            // ---- S^T = K * Q^T : shared K-frags feed both q-groups ----
            f32x4 s0[4], s1[4];
            #pragma unroll
            for (int mt = 0; mt < 4; ++mt) {
                const f16x8 kf0 = *(const f16x8*)&Ksh[(mt * 16 + lr) * KS + quad * 8];
                const f16x8 kf1 = *(const f16x8*)&Ksh[(mt * 16 + lr) * KS + 32 + quad * 8];
                if (act0) {
                    f32x4 s = (f32x4){0.f, 0.f, 0.f, 0.f};
                    s = __builtin_amdgcn_mfma_f32_16x16x32_f16(kf0, qf0a, s, 0, 0, 0);
                    s = __builtin_amdgcn_mfma_f32_16x16x32_f16(kf1, qf1a, s, 0, 0, 0);
                    s0[mt] = s;
                }
                if (act1) {
                    f32x4 s = (f32x4){0.f, 0.f, 0.f, 0.f};
                    s = __builtin_amdgcn_mfma_f32_16x16x32_f16(kf0, qf0b, s, 0, 0, 0);
                    s = __builtin_amdgcn_mfma_f32_16x16x32_f16(kf1, qf1b, s, 0, 0, 0);
                    s1[mt] = s;
                }
            }

            f16x4 pb0[4], pb1[4];
            if (act0) softmax_update(s0, m0, l0, pb0, o0, kbase, g16_0, q0, quad);
            if (act1) softmax_update(s1, m1, l1, pb1, o1, kbase, g16_1, q1, quad);

            // ---- O^T += V^T * P^T : shared V-frags feed both q-groups ----
            #pragma unroll
            for (int nt = 0; nt < 4; ++nt) {
                #pragma unroll
                for (int mi = 0; mi < 4; ++mi) {
                    const f16x4 vf = *(const f16x4*)&Vsh[(mi * 16 + lr) * VS + nt * 16 + quad * 4];
                    if (act0) o0[mi] = __builtin_amdgcn_mfma_f32_16x16x16f16(vf, pb0[nt], o0[mi], 0, 0, 0);
                    if (act1) o1[mi] = __builtin_amdgcn_mfma_f32_16x16x16f16(vf, pb1[nt], o1[mi], 0, 0, 0);
                }
            }
        }

        // raw barrier: LDS read results already consumed (lgkmcnt waits precede MFMA
        // use); prefetch global loads must NOT be drained here -> no __syncthreads
        __builtin_amdgcn_s_barrier();
        if (have_next) {
            #pragma unroll
            for (int i = 0; i < 4; ++i)
                stage_kv(Ksh, Vsh, kpre[i], vpre[i], row0 + 16 * i, c4);
        }
        __syncthreads();   // ds_writes visible; prefetch already consumed, no extra drain
    }

    // ---- epilogue: l reduce across quads, normalize, transpose via LDS, store ----
    l0 += __shfl_xor(l0, 16); l0 += __shfl_xor(l0, 32);
    l1 += __shfl_xor(l1, 16); l1 += __shfl_xor(l1, 32);
    const float inv0 = 1.0f / l0;
    const float inv1 = 1.0f / l1;

    float* Ow = Osh + wave * 32 * OS;   // per-wave private 32 x OS region
    #pragma unroll
    for (int mi = 0; mi < 4; ++mi) {
        float4 st0, st1;
        st0.x = o0[mi][0] * inv0; st0.y = o0[mi][1] * inv0;
        st0.z = o0[mi][2] * inv0; st0.w = o0[mi][3] * inv0;
        *(float4*)&Ow[lr * OS + mi * 16 + quad * 4] = st0;
        st1.x = o1[mi][0] * inv1; st1.y = o1[mi][1] * inv1;
        st1.z = o1[mi][2] * inv1; st1.w = o1[mi][3] * inv1;
        *(float4*)&Ow[(16 + lr) * OS + mi * 16 + quad * 4] = st1;
    }
    #pragma unroll
    for (int j = 0; j < 8; ++j) {
        const int qq = quad + 4 * j;        // 0..31
        const int d4 = lr * 4;
        const float4 vst = *(const float4*)&Ow[qq * OS + d4];
        *(float4*)&ob[(size_t)(wr0 + qq) * DIM + d4] = vst;
    }
}

extern "C" void kernel_launch(void* const* d_in, const int* in_sizes, int n_in,
                              void* d_out, int out_size, void* d_ws, size_t ws_size,
                              hipStream_t stream) {
    (void)in_sizes; (void)n_in; (void)out_size; (void)d_ws; (void)ws_size;
    const float* q = (const float*)d_in[0];
    const float* k = (const float*)d_in[1];
    const float* v = (const float*)d_in[2];
    float* out = (float*)d_out;
    dim3 grid(SEQ / BM, BATCH);
    swa_kernel<<<grid, dim3(NTHREADS), 0, stream>>>(q, k, v, out);
}

// Round 7
// 110.678 us; speedup vs baseline: 1.8189x; 1.7150x over previous
//
#include <hip/hip_runtime.h>

#define BATCH 16
#define SEQ   4096
#define DIM   64
#define WIN   512

constexpr int BM = 256;        // q rows per block
constexpr int BN = 64;         // keys per tile
constexpr int NTHREADS = 1024; // 16 waves; each wave owns 16 q rows (R4 body)
constexpr int KS = DIM + 8;    // Ksh row stride (f16 elems)
constexpr int VS = BN + 4;     // Vsh row stride (f16 elems)
// fold softmax scale and log2(e) into Q so p = exp2(s - m)
constexpr float QSCALE  = 0.125f * 1.44269504088896340736f;
constexpr float MASKVAL = -3.0e38f;   // << m_run init (-1e30) so masked lanes give p=0

typedef _Float16 f16x2 __attribute__((ext_vector_type(2)));
typedef _Float16 f16x4 __attribute__((ext_vector_type(4)));
typedef _Float16 f16x8 __attribute__((ext_vector_type(8)));
typedef float    f32x4 __attribute__((ext_vector_type(4)));

__device__ __forceinline__ f16x2 pk2(float a, float b) {
    return __builtin_bit_cast(f16x2, __builtin_amdgcn_cvt_pkrtz(a, b));
}

__device__ __forceinline__ void stage_kv(_Float16* __restrict__ Ksh, _Float16* __restrict__ Vsh,
                                         const float4& kv, const float4& vv,
                                         int row, int c4) {
    union { f16x4 v; f16x2 h[2]; } uk;
    uk.h[0] = pk2(kv.x, kv.y);
    uk.h[1] = pk2(kv.z, kv.w);
    *(f16x4*)&Ksh[row * KS + c4] = uk.v;
    Vsh[(c4 + 0) * VS + row] = (_Float16)vv.x;
    Vsh[(c4 + 1) * VS + row] = (_Float16)vv.y;
    Vsh[(c4 + 2) * VS + row] = (_Float16)vv.z;
    Vsh[(c4 + 3) * VS + row] = (_Float16)vv.w;
}

__global__ __launch_bounds__(NTHREADS)
void swa_kernel(const float* __restrict__ qg, const float* __restrict__ kg,
                const float* __restrict__ vg, float* __restrict__ outg) {
    // staging only: Ksh [BN][KS] f16 (9216 B) | Vsh [DIM][VS] f16 (8704 B) = 17920 B
    __shared__ __align__(16) char smem[(BN * KS + DIM * VS) * 2];
    _Float16* Ksh = (_Float16*)smem;
    _Float16* Vsh = (_Float16*)(smem + BN * KS * 2);

    const int tid  = threadIdx.x;
    const int lane = tid & 63;
    const int wave = tid >> 6;     // 0..15
    const int lr   = lane & 15;
    const int quad = lane >> 4;

    const int b     = blockIdx.y;
    const int qblk  = blockIdx.x;
    const int qrow0 = qblk * BM;
    const int wr0   = qrow0 + wave * 16;  // wave's first q row
    const int q     = wr0 + lr;           // this lane's q column (S^T layout)

    const float* qb = qg + (size_t)b * SEQ * DIM;
    const float* kb = kg + (size_t)b * SEQ * DIM;
    const float* vb = vg + (size_t)b * SEQ * DIM;
    float*       ob = outg + (size_t)b * SEQ * DIM;

    // staging thread->slot map: 1024 threads = 64 rows x 16 c4-slots, one float4 each
    const int row0 = tid >> 4;            // 0..63
    const int c4   = (tid & 15) * 4;      // 0..60

    // ---- Q B-frags straight from global into registers ----
    const float* qp = qb + (size_t)q * DIM + quad * 8;
    const float4 a0 = *(const float4*)(qp + 0);
    const float4 a1 = *(const float4*)(qp + 4);
    const float4 a2 = *(const float4*)(qp + 32);
    const float4 a3 = *(const float4*)(qp + 36);
    union { f16x8 v; f16x2 h[4]; } uq0, uq1;
    uq0.h[0] = pk2(a0.x * QSCALE, a0.y * QSCALE);
    uq0.h[1] = pk2(a0.z * QSCALE, a0.w * QSCALE);
    uq0.h[2] = pk2(a1.x * QSCALE, a1.y * QSCALE);
    uq0.h[3] = pk2(a1.z * QSCALE, a1.w * QSCALE);
    uq1.h[0] = pk2(a2.x * QSCALE, a2.y * QSCALE);
    uq1.h[1] = pk2(a2.z * QSCALE, a2.w * QSCALE);
    uq1.h[2] = pk2(a3.x * QSCALE, a3.y * QSCALE);
    uq1.h[3] = pk2(a3.z * QSCALE, a3.w * QSCALE);
    const f16x8 qf0 = uq0.v, qf1 = uq1.v;

    f32x4 o[4];
    #pragma unroll
    for (int mi = 0; mi < 4; ++mi) o[mi] = (f32x4){0.f, 0.f, 0.f, 0.f};
    float m_run = -1e30f, l_run = 0.f;

    const int t0 = (qrow0 > (WIN - 1)) ? (qrow0 - (WIN - 1)) >> 6 : 0;
    const int t1 = (qrow0 + BM - 1) >> 6;

    // ---- prologue: stage tile t0 directly ----
    {
        const size_t g0 = (size_t)(t0 * BN + row0) * DIM + c4;
        stage_kv(Ksh, Vsh, *(const float4*)&kb[g0], *(const float4*)&vb[g0], row0, c4);
    }
    __syncthreads();

    for (int t = t0; t <= t1; ++t) {
        const bool have_next = (t < t1);
        float4 kpre, vpre;
        if (have_next) {
            // issue next tile's global loads NOW; consumed after the raw barrier,
            // so they stay in flight across compute (no vmcnt(0) drain)
            const size_t g = (size_t)((t + 1) * BN + row0) * DIM + c4;
            kpre = *(const float4*)&kb[g];
            vpre = *(const float4*)&vb[g];
        }

        const int kbase = t * BN;
        // wave-level skip: no key of this tile is inside this wave's window
        const bool active = (kbase + BN - 1 >= wr0 - (WIN - 1)) && (kbase <= wr0 + 15);
        if (active) {
            // ---- S^T = K * Q^T : 4 key m-tiles x 2 k-chunks of 32 ----
            f32x4 sc[4];
            #pragma unroll
            for (int mt = 0; mt < 4; ++mt) {
                const f16x8 kf0 = *(const f16x8*)&Ksh[(mt * 16 + lr) * KS + quad * 8];
                const f16x8 kf1 = *(const f16x8*)&Ksh[(mt * 16 + lr) * KS + 32 + quad * 8];
                f32x4 s = (f32x4){0.f, 0.f, 0.f, 0.f};
                s = __builtin_amdgcn_mfma_f32_16x16x32_f16(kf0, qf0, s, 0, 0, 0);
                s = __builtin_amdgcn_mfma_f32_16x16x32_f16(kf1, qf1, s, 0, 0, 0);
                sc[mt] = s;
            }

            // ---- mask only on window-edge tiles (wave-uniform branch) ----
            const bool edge = (kbase < wr0 + 15 - (WIN - 1)) || (kbase + BN - 1 > wr0);
            if (edge) {
                #pragma unroll
                for (int mt = 0; mt < 4; ++mt) {
                    #pragma unroll
                    for (int r = 0; r < 4; ++r) {
                        const int key = kbase + mt * 16 + quad * 4 + r;
                        sc[mt][r] = ((unsigned)(q - key) < (unsigned)WIN) ? sc[mt][r] : MASKVAL;
                    }
                }
            }

            // ---- online softmax (one q per lane) ----
            float mt_ = MASKVAL;
            #pragma unroll
            for (int mtile = 0; mtile < 4; ++mtile)
                #pragma unroll
                for (int r = 0; r < 4; ++r) mt_ = fmaxf(mt_, sc[mtile][r]);
            mt_ = fmaxf(mt_, __shfl_xor(mt_, 16));
            mt_ = fmaxf(mt_, __shfl_xor(mt_, 32));
            const float mn    = fmaxf(m_run, mt_);
            const float alpha = exp2f(m_run - mn);
            m_run = mn;

            f16x4 pb[4];
            float ls = 0.f;
            #pragma unroll
            for (int nt = 0; nt < 4; ++nt) {
                const float p0 = exp2f(sc[nt][0] - mn);
                const float p1 = exp2f(sc[nt][1] - mn);
                const float p2 = exp2f(sc[nt][2] - mn);
                const float p3 = exp2f(sc[nt][3] - mn);
                ls += (p0 + p1) + (p2 + p3);
                union { f16x4 v; f16x2 h[2]; } up;
                up.h[0] = pk2(p0, p1);
                up.h[1] = pk2(p2, p3);
                pb[nt] = up.v;
            }
            l_run = l_run * alpha + ls;
            #pragma unroll
            for (int mi = 0; mi < 4; ++mi) o[mi] = o[mi] * alpha;

            // ---- O^T += V^T * P^T : P^T (C-layout) is the B-operand of 16x16x16 ----
            #pragma unroll
            for (int nt = 0; nt < 4; ++nt) {
                #pragma unroll
                for (int mi = 0; mi < 4; ++mi) {
                    const f16x4 vf = *(const f16x4*)&Vsh[(mi * 16 + lr) * VS + nt * 16 + quad * 4];
                    o[mi] = __builtin_amdgcn_mfma_f32_16x16x16f16(vf, pb[nt], o[mi], 0, 0, 0);
                }
            }
        }

        // raw barrier: LDS read results already consumed (lgkmcnt waits precede MFMA
        // use); prefetch global loads must NOT be drained here -> no __syncthreads
        __builtin_amdgcn_s_barrier();
        if (have_next) {
            stage_kv(Ksh, Vsh, kpre, vpre, row0, c4);
        }
        __syncthreads();   // ds_writes visible; prefetch already consumed, no extra drain
    }

    // ---- epilogue: l reduce across quads, normalize, direct store (no LDS) ----
    // O^T C-layout: lane (lr,quad) holds O[d = mi*16 + quad*4 + r][q = lr] — for fixed
    // (lr,mi) the 4 r-values are contiguous in d => float4 store at q*DIM + mi*16 + quad*4.
    l_run += __shfl_xor(l_run, 16);
    l_run += __shfl_xor(l_run, 32);
    const float inv = 1.0f / l_run;
    #pragma unroll
    for (int mi = 0; mi < 4; ++mi) {
        float4 st;
        st.x = o[mi][0] * inv; st.y = o[mi][1] * inv;
        st.z = o[mi][2] * inv; st.w = o[mi][3] * inv;
        *(float4*)&ob[(size_t)q * DIM + mi * 16 + quad * 4] = st;
    }
}

extern "C" void kernel_launch(void* const* d_in, const int* in_sizes, int n_in,
                              void* d_out, int out_size, void* d_ws, size_t ws_size,
                              hipStream_t stream) {
    (void)in_sizes; (void)n_in; (void)out_size; (void)d_ws; (void)ws_size;
    const float* q = (const float*)d_in[0];
    const float* k = (const float*)d_in[1];
    const float* v = (const float*)d_in[2];
    float* out = (float*)d_out;
    dim3 grid(SEQ / BM, BATCH);
    swa_kernel<<<grid, dim3(NTHREADS), 0, stream>>>(q, k, v, out);
}